// Round 10
// baseline (11015.916 us; speedup 1.0000x reference)
//
#include <hip/hip_runtime.h>
#include <cstdint>
#include <cstddef>

#define B_ 256
#define S_ 512

typedef _Float16 f16;
typedef _Float16 f16x8 __attribute__((ext_vector_type(8)));
typedef float f32x4 __attribute__((ext_vector_type(4)));
using u32 = unsigned int;
using u16 = unsigned short;
using u64 = unsigned long long;

#define TAGX   0x555u
#define MAGIC_ 0x13579BDFu

__device__ __forceinline__ float sigf(float x) { return 1.f / (1.f + __expf(-x)); }
__device__ __forceinline__ float tanh_f(float x) {
  x = fminf(15.f, fmaxf(-15.f, x));
  const float e = __expf(-2.f * x);
  return (1.f - e) / (1.f + e);
}
__device__ __forceinline__ f16x8 cvt_f16x8(float4 a, float4 b) {
  f16x8 t;
  t[0] = (f16)a.x; t[1] = (f16)a.y; t[2] = (f16)a.z; t[3] = (f16)a.w;
  t[4] = (f16)b.x; t[5] = (f16)b.y; t[6] = (f16)b.z; t[7] = (f16)b.w;
  return t;
}

// ---------------------------------------------------------------------------
// x transpose+convert: x[b][t][64] fp32 -> xT[t][b][64] f16
// ---------------------------------------------------------------------------
__global__ __launch_bounds__(256) void transpose_x(
    const float* __restrict__ x, f16* __restrict__ xT)
{
  const int t = blockIdx.x;
  const int col = threadIdx.x & 63;
  const int r0 = threadIdx.x >> 6;
  for (int it = 0; it < 64; ++it) {
    const int row = (it << 2) + r0;
    xT[((size_t)t * 256 + row) * 64 + col] =
        (f16)x[((size_t)row * S_ + t) * 64 + col];
  }
}

// ---------------------------------------------------------------------------
// Persistent fused BiLSTM layer. 128 wgs x 512 thr (8 waves, 2/SIMD), 1/CU.
// wg = (dir,bg,sl): 16 batch rows x 256 gate cols (sl in 0..3) = 64 h-units.
// Wave w: gate gi=w>>1, unit-half uh=w&1 (32 cols = 2 nt-tiles of 16).
// Weights in registers (W_ih f16; W_hh f16 hi + lo*2^10). 4-wg tagged-f32
// exchange (sc1, RELAXED, self-validating step tag in low 11 mantissa bits).
// Block swizzle co-locates each 4-wg group on one XCD (perf only; protocol
// is mapping-independent).
// ---------------------------------------------------------------------------
template<int L, int KIN>
__global__ __launch_bounds__(512, 1) void lstm_layer(
    const f16* __restrict__ xT,     // [512][256][64]   (L0 input)
    f16* __restrict__ hA,           // [512][256][512]
    f16* __restrict__ aux,          // [2][256][256][256]
    f16* __restrict__ l2out,        // [256][512]
    u64* __restrict__ exch,         // tagged ring [2 par][2 dir][256 b][128]
    u32* __restrict__ xprog,        // [2][64]
    const float* __restrict__ w_ih, // [2][1024][KIN]
    const float* __restrict__ w_hh, // [2][1024][256]
    const float* __restrict__ bias) // [2][1024]
{
  constexpr int GPR = KIN / 8;
  constexpr int LG  = (KIN == 512) ? 6 : 3;
  constexpr int NG  = 16 * GPR;
  constexpr int XI  = (NG + 511) / 512;
  __shared__ __align__(16) f16 x_s[16 * KIN];
  __shared__ __align__(16) f16 h_s[16 * 256];
  __shared__ float gates_s[64 * 66];
  constexpr int PADB = 90112 - 16 * KIN * 2 - 16 * 256 * 2 - 64 * 66 * 4;
  __shared__ char pad_[PADB];       // force 1 wg/CU

  const int tid = threadIdx.x;
  const int lane = tid & 63, w = tid >> 6;
  const int l15 = lane & 15, l4 = lane >> 4;
  const int gi = w >> 1, uh = w & 1;
  const int phys = blockIdx.x;
  const int xcd = phys & 7, slot = phys >> 3;
  const int gp = slot >> 2, sl = slot & 3;
  const int grp = (gp << 3) | xcd;          // 0..31, 4 wgs each, same XCD
  const int dirv = grp >> 4, bg = grp & 15;
  if ((int)blockIdx.x == -1) pad_[tid] = 0;

  // ---- weight slices -> registers ----
  f16x8 bih[2][KIN / 32];
  f16x8 bhhH[2][8], bhhL[2][8];
#pragma unroll
  for (int nt = 0; nt < 2; ++nt) {
    const int grow = (gi << 8) + (sl << 6) + (uh << 5) + (nt << 4) + l15;
    const float* pih = w_ih + ((size_t)(dirv << 10) + grow) * KIN + (l4 << 3);
#pragma unroll
    for (int kt = 0; kt < KIN / 32; ++kt) {
      const float* p = pih + (kt << 5);
      bih[nt][kt] = cvt_f16x8(*(const float4*)p, *(const float4*)(p + 4));
    }
    const float* phh = w_hh + ((size_t)(dirv << 10) + grow) * 256 + (l4 << 3);
#pragma unroll
    for (int kt = 0; kt < 8; ++kt) {
      const float* p = phh + (kt << 5);
      float wf[8];
      *(float4*)&wf[0] = *(const float4*)p;
      *(float4*)&wf[4] = *(const float4*)(p + 4);
      f16x8 hi, lo;
#pragma unroll
      for (int j = 0; j < 8; ++j) {
        hi[j] = (f16)wf[j];
        lo[j] = (f16)((wf[j] - (float)hi[j]) * 1024.f);
      }
      bhhH[nt][kt] = hi;
      bhhL[nt][kt] = lo;
    }
  }

  // ---- per-thread cell constants: (crow, u0), (crow, u0+1) ----
  const int crow = tid >> 5;                // 0..15 (also consumer stage row)
  const int u0 = (tid & 31) << 1;           // 0..62 even, wg-local unit
  float bv[4][2];
#pragma unroll
  for (int g = 0; g < 4; ++g)
#pragma unroll
    for (int j = 0; j < 2; ++j)
      bv[g][j] = bias[(dirv << 10) + (g << 8) + (sl << 6) + u0 + j];
  float cs0 = 0.f, cs1 = 0.f;
  const int sg8 = tid & 31;                 // consumer stage granule

  auto xsrc = [&](int t, int b, int g) -> const f16* {
    if constexpr (L == 0) {
      return xT + ((size_t)t * 256 + b) * 64 + (g << 3);
    } else if constexpr (L == 1) {
      return hA + ((size_t)t * 256 + b) * 512 + (g << 3);
    } else {
      const int c0 = g << 3;
      if (c0 < 256)
        return (t < 256) ? aux + ((size_t)t * 256 + b) * 256 + c0
                         : hA + ((size_t)t * 256 + b) * 512 + c0;
      const int u = c0 - 256;
      return (t >= 256) ? aux + ((size_t)(256 + (511 - t)) * 256 + b) * 256 + u
                        : hA + ((size_t)t * 256 + b) * 512 + 256 + u;
    }
  };

#define X_MFMA(A0, A1)                                                         \
  {                                                                            \
    _Pragma("unroll")                                                          \
    for (int kt = 0; kt < KIN / 32; ++kt) {                                    \
      const int gg = ((kt << 2) + l4) ^ (l15 & 7);                             \
      const f16x8 a = *(const f16x8*)&x_s[l15 * KIN + (gg << 3)];              \
      A0 = __builtin_amdgcn_mfma_f32_16x16x32_f16(a, bih[0][kt], A0, 0, 0, 0); \
      A1 = __builtin_amdgcn_mfma_f32_16x16x32_f16(a, bih[1][kt], A1, 0, 0, 0); \
    }                                                                          \
  }

  // ---- prologue: stage x(0), compute its x-part ----
  f16x8 xreg[XI];
  {
    const int t0 = dirv ? (S_ - 1) : 0;
#pragma unroll
    for (int i = 0; i < XI; ++i) {
      const int G = tid + (i << 9);
      if (NG < 512 && G >= NG) break;
      const int row = G >> LG, g = G & (GPR - 1);
      xreg[i] = *(const f16x8*)xsrc(t0, (bg << 4) + row, g);
    }
#pragma unroll
    for (int i = 0; i < XI; ++i) {
      const int G = tid + (i << 9);
      if (NG < 512 && G >= NG) break;
      const int row = G >> LG, g = G & (GPR - 1);
      *(f16x8*)&x_s[row * KIN + ((g ^ (row & 7)) << 3)] = xreg[i];
    }
  }
  __syncthreads();
  f32x4 accx0 = {}, accx1 = {};
  X_MFMA(accx0, accx1);

  for (int s = 0; s < S_; ++s) {
    const int t_or = dirv ? (S_ - 1 - s) : s;
    const bool pf = (s + 1 < S_);

    // ---- issue x prefetch for step s+1 ----
    if (pf) {
      const int t_nx = dirv ? (t_or - 1) : (t_or + 1);
#pragma unroll
      for (int i = 0; i < XI; ++i) {
        const int G = tid + (i << 9);
        if (NG < 512 && G >= NG) break;
        const int row = G >> LG, g = G & (GPR - 1);
        xreg[i] = *(const f16x8*)xsrc(t_nx, (bg << 4) + row, g);
      }
    }

    // ---- L1 crossover gate: before first in-place write ----
    if constexpr (L == 1) {
      if (s == 256) {
        if (tid < 64) {
          const u32* pw = xprog + (1 - dirv) * 64 + tid;
          while (__hip_atomic_load(pw, __ATOMIC_RELAXED, __HIP_MEMORY_SCOPE_AGENT) != MAGIC_)
            __builtin_amdgcn_s_sleep(2);
        }
        __syncthreads();
      }
    }

    // ---- stage h(s-1): tagged poll (4 u64 / thread -> one f16x8 granule) --
    if (s > 0) {
      const u32 tagp = ((u32)(L * 512 + s - 1) ^ TAGX) & 0x7FFu;
      const u64* pb = exch + ((size_t)(((s - 1) & 1) * 2 + dirv)) * 256 * 128
                      + ((bg << 4) + crow) * 128 + (sg8 << 2);
      u64 a[4];
      for (int tr = 0;; ++tr) {
#pragma unroll
        for (int k = 0; k < 4; ++k)
          a[k] = __hip_atomic_load(pb + k, __ATOMIC_RELAXED, __HIP_MEMORY_SCOPE_AGENT);
        bool ok = true;
#pragma unroll
        for (int k = 0; k < 4; ++k)
          ok &= (((u32)a[k] & 0x7FFu) == tagp) & (((u32)(a[k] >> 32) & 0x7FFu) == tagp);
        if (ok) break;
        if (tr >= 3) __builtin_amdgcn_s_sleep(1);
      }
      f16x8 hh;
#pragma unroll
      for (int k = 0; k < 4; ++k) {
        hh[2 * k]     = (f16)__builtin_bit_cast(float, (u32)a[k] & 0xFFFFF800u);
        hh[2 * k + 1] = (f16)__builtin_bit_cast(float, (u32)(a[k] >> 32) & 0xFFFFF800u);
      }
      *(f16x8*)&h_s[(crow << 8) + ((sg8 ^ (crow & 7)) << 3)] = hh;
    }
    __syncthreads();                               // h_s staged

    // ---- MFMAs: acc = accx + h@WhhHi + (h@WhhLo)/1024 ----
    f32x4 acc0 = accx0, acc1 = accx1;
    if (s > 0) {
      f32x4 aL0 = {}, aL1 = {};
#pragma unroll
      for (int kt = 0; kt < 8; ++kt) {
        const int gg = ((kt << 2) + l4) ^ (l15 & 7);
        const f16x8 a = *(const f16x8*)&h_s[(l15 << 8) + (gg << 3)];
        acc0 = __builtin_amdgcn_mfma_f32_16x16x32_f16(a, bhhH[0][kt], acc0, 0, 0, 0);
        acc1 = __builtin_amdgcn_mfma_f32_16x16x32_f16(a, bhhH[1][kt], acc1, 0, 0, 0);
        aL0 = __builtin_amdgcn_mfma_f32_16x16x32_f16(a, bhhL[0][kt], aL0, 0, 0, 0);
        aL1 = __builtin_amdgcn_mfma_f32_16x16x32_f16(a, bhhL[1][kt], aL1, 0, 0, 0);
      }
      acc0 += aL0 * (1.f / 1024.f);
      acc1 += aL1 * (1.f / 1024.f);
    }

    // ---- gate preacts -> LDS. D frag: row=(l4)*4+r, col=l15 ----
#pragma unroll
    for (int r = 0; r < 4; ++r) {
      const int row = (l4 << 2) + r;
      gates_s[((gi << 4) + row) * 66 + (uh << 5) + l15] = acc0[r];
      gates_s[((gi << 4) + row) * 66 + (uh << 5) + 16 + l15] = acc1[r];
    }
    __syncthreads();

    // ---- cell update: (crow, u0), (crow, u0+1) ----
    float hv[2];
    {
      float css[2] = { cs0, cs1 };
#pragma unroll
      for (int j = 0; j < 2; ++j) {
        const int u = u0 + j;
        const float gI = gates_s[(0 * 16 + crow) * 66 + u] + bv[0][j];
        const float gF = gates_s[(1 * 16 + crow) * 66 + u] + bv[1][j];
        const float gG = gates_s[(2 * 16 + crow) * 66 + u] + bv[2][j];
        const float gO = gates_s[(3 * 16 + crow) * 66 + u] + bv[3][j];
        float cc = sigf(gF) * css[j] + sigf(gI) * tanh_f(gG);
        css[j] = cc;
        hv[j] = sigf(gO) * tanh_f(cc);
      }
      cs0 = css[0]; cs1 = css[1];
    }

    // ---- publish h(s) (tagged exch first), then bulk stores ----
    if (L == 1 && s >= 253) asm volatile("s_waitcnt vmcnt(0)" ::: "memory");
    {
      const u32 tagc = ((u32)(L * 512 + s) ^ TAGX) & 0x7FFu;
      const u32 w0 = ((__builtin_bit_cast(u32, hv[0]) + 0x400u) & 0xFFFFF800u) | tagc;
      const u32 w1 = ((__builtin_bit_cast(u32, hv[1]) + 0x400u) & 0xFFFFF800u) | tagc;
      const u64 pk = (u64)w0 | ((u64)w1 << 32);
      const int b = (bg << 4) + crow;
      const size_t eidx = ((size_t)((s & 1) * 2 + dirv)) * 256 * 128
                          + b * 128 + (sl << 5) + (u0 >> 1);
      __hip_atomic_store(exch + eidx, pk, __ATOMIC_RELAXED, __HIP_MEMORY_SCOPE_AGENT);

      union { u16 hw[2]; u32 pkh; } uhh;
      uhh.hw[0] = __builtin_bit_cast(u16, (f16)hv[0]);
      uhh.hw[1] = __builtin_bit_cast(u16, (f16)hv[1]);
      const int uoff = (dirv << 7) + (sl << 5) + (u0 >> 1);
      if constexpr (L == 0) {
        ((u32*)hA)[((size_t)t_or * 256 + b) * 256 + uoff] = uhh.pkh;
      } else if constexpr (L == 1) {
        if (s < 256)
          ((u32*)aux)[((size_t)(dirv * 256 + s) * 256 + b) * 128 + (sl << 5) + (u0 >> 1)] = uhh.pkh;
        else
          ((u32*)hA)[((size_t)t_or * 256 + b) * 256 + uoff] = uhh.pkh;
      } else {
        if (t_or == S_ - 1)
          ((u32*)l2out)[(size_t)b * 256 + uoff] = uhh.pkh;
      }
    }

    // ---- L1: crossover MAGIC after h(254) reads secured ----
    if constexpr (L == 1) {
      if (s == 254) {
        asm volatile("s_waitcnt vmcnt(0)" ::: "memory");
        __syncthreads();
        if (tid == 0)
          __hip_atomic_store(xprog + dirv * 64 + (bg << 2) + sl, MAGIC_,
                             __ATOMIC_RELAXED, __HIP_MEMORY_SCOPE_AGENT);
      }
    }

    // ---- write x_s for s+1 and pre-compute its x-part ----
    if (pf) {
#pragma unroll
      for (int i = 0; i < XI; ++i) {
        const int G = tid + (i << 9);
        if (NG < 512 && G >= NG) break;
        const int row = G >> LG, g = G & (GPR - 1);
        *(f16x8*)&x_s[row * KIN + ((g ^ (row & 7)) << 3)] = xreg[i];
      }
      __syncthreads();
      accx0 = (f32x4){}; accx1 = (f32x4){};
      X_MFMA(accx0, accx1);
    }
  }
#undef X_MFMA
}

// ---------------------------------------------------------------------------
__global__ __launch_bounds__(256) void fc_head(
    const f16* __restrict__ l2out,   // [B][512]
    const float* __restrict__ fc1_w, const float* __restrict__ fc1_b,
    const float* __restrict__ fc2_w, const float* __restrict__ fc2_b,
    const float* __restrict__ fc3_w, const float* __restrict__ fc3_b,
    float* __restrict__ out)
{
  __shared__ float last[512];
  __shared__ float h1[256];
  __shared__ float h2[128];
  const int b = blockIdx.x;
  const int t = threadIdx.x;
  for (int i = t; i < 512; i += 256)
    last[i] = (float)l2out[(size_t)b * 512 + i];
  __syncthreads();
  {
    float a = fc1_b[t];
    for (int k = 0; k < 512; ++k) a = fmaf(last[k], fc1_w[t * 512 + k], a);
    h1[t] = fmaxf(a, 0.f);
  }
  __syncthreads();
  if (t < 128) {
    float a = fc2_b[t];
    for (int k = 0; k < 256; ++k) a = fmaf(h1[k], fc2_w[t * 256 + k], a);
    h2[t] = fmaxf(a, 0.f);
  }
  __syncthreads();
  if (t == 0) {
    float a = fc3_b[0];
    for (int k = 0; k < 128; ++k) a = fmaf(h2[k], fc3_w[k], a);
    out[b] = a;
  }
}

__global__ void sentinel(float* out, int n, float v) {
  const int i = blockIdx.x * blockDim.x + threadIdx.x;
  if (i < n) out[i] = v;
}

// ---------------------------------------------------------------------------
extern "C" void kernel_launch(void* const* d_in, const int* in_sizes, int n_in,
                              void* d_out, int out_size, void* d_ws, size_t ws_size,
                              hipStream_t stream) {
  (void)in_sizes; (void)n_in;
  const float* x      = (const float*)d_in[0];
  const float* w_ih0  = (const float*)d_in[1];
  const float* w_hh0  = (const float*)d_in[2];
  const float* b0     = (const float*)d_in[3];
  const float* w_ih_r = (const float*)d_in[4];
  const float* w_hh_r = (const float*)d_in[5];
  const float* b_r    = (const float*)d_in[6];
  const float* fc1_w  = (const float*)d_in[7];
  const float* fc1_b  = (const float*)d_in[8];
  const float* fc2_w  = (const float*)d_in[9];
  const float* fc2_b  = (const float*)d_in[10];
  const float* fc3_w  = (const float*)d_in[11];
  const float* fc3_b  = (const float*)d_in[12];
  float* out = (float*)d_out;

  // ---- workspace carve (bytes) ----
  const size_t off_hA    = 0;
  const size_t off_aux   = off_hA    + (size_t)512*256*512*2;      // 128 MiB
  const size_t off_xT    = off_aux   + (size_t)2*256*256*256*2;    // +64 MiB
  const size_t off_l2o   = off_xT    + (size_t)512*256*64*2;       // +16 MiB
  const size_t off_exch  = off_l2o   + (size_t)256*512*2;          // +0.25 MiB
  const size_t off_xprog = off_exch  + (size_t)2*2*256*128*8;      // +1 MiB
  const size_t need      = off_xprog + 1024;
  if (ws_size < need) {
    sentinel<<<1, 256, 0, stream>>>(out, out_size, (float)(ws_size >> 20));
    return;
  }
  char* ws = (char*)d_ws;
  f16* hA    = (f16*)(ws + off_hA);
  f16* aux   = (f16*)(ws + off_aux);
  f16* xT    = (f16*)(ws + off_xT);
  f16* l2out = (f16*)(ws + off_l2o);
  u64* exch  = (u64*)(ws + off_exch);
  u32* xprog = (u32*)(ws + off_xprog);

  // kill stale tags / MAGIC from previous replays (0xAA aliases no (L,s) tag)
  hipMemsetAsync(ws + off_exch, 0xAA, (size_t)2*2*256*128*8 + 1024, stream);

  transpose_x<<<512, 256, 0, stream>>>(x, xT);

  lstm_layer<0, 64><<<128, 512, 0, stream>>>(
      xT, hA, aux, l2out, exch, xprog, w_ih0, w_hh0, b0);
  lstm_layer<1, 512><<<128, 512, 0, stream>>>(
      xT, hA, aux, l2out, exch, xprog, w_ih_r, w_hh_r, b_r);
  lstm_layer<2, 512><<<128, 512, 0, stream>>>(
      xT, hA, aux, l2out, exch, xprog,
      w_ih_r + (size_t)2 * 1024 * 512, w_hh_r + (size_t)2 * 1024 * 256,
      b_r + 2048);

  fc_head<<<B_, 256, 0, stream>>>(l2out, fc1_w, fc1_b, fc2_w, fc2_b, fc3_w, fc3_b, out);
}

// Round 11
// 5656.815 us; speedup vs baseline: 1.9474x; 1.9474x over previous
//
#include <hip/hip_runtime.h>
#include <cstdint>
#include <cstddef>

#define B_ 256
#define S_ 512

typedef _Float16 f16;
typedef _Float16 f16x8 __attribute__((ext_vector_type(8)));
typedef float f32x4 __attribute__((ext_vector_type(4)));
using u32 = unsigned int;
using u16 = unsigned short;
using u64 = unsigned long long;

#define TAGX   0x555u
#define MAGIC_ 0x13579BDFu

__device__ __forceinline__ float sigf(float x) { return 1.f / (1.f + __expf(-x)); }
__device__ __forceinline__ float tanh_f(float x) {
  x = fminf(15.f, fmaxf(-15.f, x));
  const float e = __expf(-2.f * x);
  return (1.f - e) / (1.f + e);
}
__device__ __forceinline__ f16x8 cvt_f16x8(float4 a, float4 b) {
  f16x8 t;
  t[0] = (f16)a.x; t[1] = (f16)a.y; t[2] = (f16)a.z; t[3] = (f16)a.w;
  t[4] = (f16)b.x; t[5] = (f16)b.y; t[6] = (f16)b.z; t[7] = (f16)b.w;
  return t;
}

// ---------------------------------------------------------------------------
// x transpose+convert: x[b][t][64] fp32 -> xT[t][b][64] f16
// ---------------------------------------------------------------------------
__global__ __launch_bounds__(256) void transpose_x(
    const float* __restrict__ x, f16* __restrict__ xT)
{
  const int t = blockIdx.x;
  const int col = threadIdx.x & 63;
  const int r0 = threadIdx.x >> 6;
  for (int it = 0; it < 64; ++it) {
    const int row = (it << 2) + r0;
    xT[((size_t)t * 256 + row) * 64 + col] =
        (f16)x[((size_t)row * S_ + t) * 64 + col];
  }
}

// ---------------------------------------------------------------------------
// Persistent fused BiLSTM layer. 256 thr/wg, 1 wave/SIMD (512-VGPR budget).
// NSL = exchange parties per (dir,bg) group: 8 (r7-proven, L1/L2) or
// 4 (L0: K=64 frees VGPR -> 256 gate cols/wg, full hi/lo W_hh).
// Tagged-f32 parity-ring exchange (sc1 RELAXED, 11-bit step tag in low
// mantissa). Consumer: contiguous 8xu64/thread with retained-freshness
// re-poll. Weights in registers; x-part MFMAs hidden in publish->poll window.
// ---------------------------------------------------------------------------
template<int L, int KIN, int NSL>
__global__ __launch_bounds__(256, 1) void lstm_layer(
    const f16* __restrict__ xT,     // [512][256][64]   (L0 input)
    f16* __restrict__ hA,           // [512][256][512]
    f16* __restrict__ aux,          // [2][256][256][256]
    f16* __restrict__ l2out,        // [256][512]
    u64* __restrict__ exch,         // tagged ring [2 par][2 dir][256 b][128]
    u32* __restrict__ xprog,        // [2][128]
    const float* __restrict__ w_ih, // [2][1024][KIN]
    const float* __restrict__ w_hh, // [2][1024][256]
    const float* __restrict__ bias) // [2][1024]
{
  constexpr int GPR = KIN / 8;
  constexpr int LG  = (KIN == 512) ? 6 : 3;
  constexpr int NG  = 16 * GPR;
  constexpr int XI  = (NG + 255) / 256;
  constexpr int UN  = 256 / NSL;            // units per wg
  constexpr int NT  = UN / 16;              // 16-col tiles per wave
  constexpr int PP  = UN / 32;              // cell items per thread
  constexpr int LU  = (PP == 2) ? 5 : 4;
  constexpr int ST  = UN + ((UN == 64) ? 2 : 1);

  __shared__ __align__(16) f16 x_s[16 * KIN];
  __shared__ __align__(16) f16 h_s[16 * 256];
  __shared__ float gates_s[64 * ST];
  __shared__ char pad_[81920];              // keep 1 wg/CU

  const int tid = threadIdx.x;
  const int lane = tid & 63, w = tid >> 6;  // w = gate index
  const int l15 = lane & 15, l4 = lane >> 4;
  const int phys = blockIdx.x;
  int dirv, bg, sl;
  if constexpr (NSL == 8) {
    const int wg = ((phys & 7) << 5) | (phys >> 3);   // r7 swizzle
    dirv = wg >> 7; bg = (wg >> 3) & 15; sl = wg & 7;
  } else {
    const int xcd = phys & 7, slot = phys >> 3;       // 128 wgs
    const int grp = (xcd << 2) | (slot >> 2);         // 4 wgs share an XCD
    dirv = grp >> 4; bg = grp & 15; sl = slot & 3;
  }
  if ((int)blockIdx.x == -1) pad_[tid] = 0;

  // ---- weight slices -> registers ----
  f16x8 bih[NT][KIN / 32];
  f16x8 bhhH[NT][8], bhhL[NT][8];
#pragma unroll
  for (int nt = 0; nt < NT; ++nt) {
    const int grow = (w << 8) + sl * UN + (nt << 4) + l15;   // gate col
    const float* pih = w_ih + ((size_t)(dirv << 10) + grow) * KIN + (l4 << 3);
#pragma unroll
    for (int kt = 0; kt < KIN / 32; ++kt) {
      const float* p = pih + (kt << 5);
      bih[nt][kt] = cvt_f16x8(*(const float4*)p, *(const float4*)(p + 4));
    }
    const float* phh = w_hh + ((size_t)(dirv << 10) + grow) * 256 + (l4 << 3);
#pragma unroll
    for (int kt = 0; kt < 8; ++kt) {
      const float* p = phh + (kt << 5);
      float wf[8];
      *(float4*)&wf[0] = *(const float4*)p;
      *(float4*)&wf[4] = *(const float4*)(p + 4);
      f16x8 hi, lo;
#pragma unroll
      for (int j = 0; j < 8; ++j) {
        hi[j] = (f16)wf[j];
        lo[j] = (f16)((wf[j] - (float)hi[j]) * 1024.f);
      }
      bhhH[nt][kt] = hi;
      bhhL[nt][kt] = lo;
    }
  }

  // ---- per-thread cell constants ----
  const int upair = tid & ((1 << LU) - 1);
  const int u0 = upair << 1;
  float bv[4][2];
#pragma unroll
  for (int g = 0; g < 4; ++g)
#pragma unroll
    for (int j = 0; j < 2; ++j)
      bv[g][j] = bias[(dirv << 10) + (g << 8) + sl * UN + u0 + j];
  float cs[PP][2];
#pragma unroll
  for (int pp = 0; pp < PP; ++pp) { cs[pp][0] = 0.f; cs[pp][1] = 0.f; }

  auto xsrc = [&](int t, int b, int g) -> const f16* {
    if constexpr (L == 0) {
      return xT + ((size_t)t * 256 + b) * 64 + (g << 3);
    } else if constexpr (L == 1) {
      return hA + ((size_t)t * 256 + b) * 512 + (g << 3);
    } else {
      const int c0 = g << 3;
      if (c0 < 256)
        return (t < 256) ? aux + ((size_t)t * 256 + b) * 256 + c0
                         : hA + ((size_t)t * 256 + b) * 512 + c0;
      const int u = c0 - 256;
      return (t >= 256) ? aux + ((size_t)(256 + (511 - t)) * 256 + b) * 256 + u
                        : hA + ((size_t)t * 256 + b) * 512 + 256 + u;
    }
  };

#define X_MFMA(ACC)                                                            \
  {                                                                            \
    _Pragma("unroll")                                                          \
    for (int kt = 0; kt < KIN / 32; ++kt) {                                    \
      const int gg = ((kt << 2) + l4) ^ (l15 & 7);                             \
      const f16x8 a = *(const f16x8*)&x_s[l15 * KIN + (gg << 3)];              \
      _Pragma("unroll")                                                        \
      for (int nt = 0; nt < NT; ++nt)                                          \
        ACC[nt] = __builtin_amdgcn_mfma_f32_16x16x32_f16(a, bih[nt][kt], ACC[nt], 0, 0, 0); \
    }                                                                          \
  }

  // ---- prologue: stage x(0), compute its x-part ----
  f16x8 xreg[XI];
  {
    const int t0 = dirv ? (S_ - 1) : 0;
#pragma unroll
    for (int i = 0; i < XI; ++i) {
      const int G = tid + (i << 8);
      if (NG < 256 && G >= NG) break;
      const int row = G >> LG, g = G & (GPR - 1);
      xreg[i] = *(const f16x8*)xsrc(t0, (bg << 4) + row, g);
    }
#pragma unroll
    for (int i = 0; i < XI; ++i) {
      const int G = tid + (i << 8);
      if (NG < 256 && G >= NG) break;
      const int row = G >> LG, g = G & (GPR - 1);
      *(f16x8*)&x_s[row * KIN + ((g ^ (row & 7)) << 3)] = xreg[i];
    }
  }
  __syncthreads();
  f32x4 accx[NT];
#pragma unroll
  for (int nt = 0; nt < NT; ++nt) accx[nt] = (f32x4){};
  X_MFMA(accx);

  for (int s = 0; s < S_; ++s) {
    const int t_or = dirv ? (S_ - 1 - s) : s;
    const bool pf = (s + 1 < S_);

    // ---- issue x prefetch for step s+1 ----
    if (pf) {
      const int t_nx = dirv ? (t_or - 1) : (t_or + 1);
#pragma unroll
      for (int i = 0; i < XI; ++i) {
        const int G = tid + (i << 8);
        if (NG < 256 && G >= NG) break;
        const int row = G >> LG, g = G & (GPR - 1);
        xreg[i] = *(const f16x8*)xsrc(t_nx, (bg << 4) + row, g);
      }
    }

    // ---- L1 crossover gate: before first in-place write ----
    if constexpr (L == 1) {
      if (s == 256) {
        if (tid < 128) {
          const u32* pw = xprog + (1 - dirv) * 128 + tid;
          while (__hip_atomic_load(pw, __ATOMIC_RELAXED, __HIP_MEMORY_SCOPE_AGENT) != MAGIC_)
            __builtin_amdgcn_s_sleep(2);
        }
        __syncthreads();
      }
    }

    // ---- stage h(s-1): contiguous 8xu64/thread, retained-freshness poll ---
    if (s > 0) {
      const u32 tagp = ((u32)(L * 512 + s - 1) ^ TAGX) & 0x7FFu;
      const int prow = tid >> 4;
      const u64* pb = exch + ((size_t)(((s - 1) & 1) * 2 + dirv)) * 256 * 128
                      + ((bg << 4) + prow) * 128 + ((tid & 15) << 3);
      u64 a[8];
      u32 freshm = 0;
      for (int tr = 0;; ++tr) {
#pragma unroll
        for (int k = 0; k < 8; ++k) {
          if (!((freshm >> k) & 1u)) {
            const u64 v = __hip_atomic_load(pb + k, __ATOMIC_RELAXED, __HIP_MEMORY_SCOPE_AGENT);
            a[k] = v;
            if ((((u32)v & 0x7FFu) == tagp) & (((u32)(v >> 32) & 0x7FFu) == tagp))
              freshm |= (1u << k);
          }
        }
        if (freshm == 0xFFu) break;
        if (tr >= 1) __builtin_amdgcn_s_sleep(1);
      }
#pragma unroll
      for (int d = 0; d < 2; ++d) {
        const int g8 = ((tid & 15) << 1) + d;
        f16x8 hh;
#pragma unroll
        for (int m = 0; m < 4; ++m) {
          const u64 v = a[d * 4 + m];
          hh[2 * m]     = (f16)__builtin_bit_cast(float, (u32)v & 0xFFFFF800u);
          hh[2 * m + 1] = (f16)__builtin_bit_cast(float, (u32)(v >> 32) & 0xFFFFF800u);
        }
        *(f16x8*)&h_s[(prow << 8) + ((g8 ^ (prow & 7)) << 3)] = hh;
      }
    }
    __syncthreads();                               // h_s staged

    // ---- MFMAs: acc = accx + h@WhhHi + (h@WhhLo)/1024 ----
    f32x4 acc[NT], accL[NT];
#pragma unroll
    for (int nt = 0; nt < NT; ++nt) { acc[nt] = accx[nt]; accL[nt] = (f32x4){}; }
    if (s > 0) {
#pragma unroll
      for (int kt = 0; kt < 8; ++kt) {
        const int gg = ((kt << 2) + l4) ^ (l15 & 7);
        const f16x8 a = *(const f16x8*)&h_s[(l15 << 8) + (gg << 3)];
#pragma unroll
        for (int nt = 0; nt < NT; ++nt) {
          acc[nt] = __builtin_amdgcn_mfma_f32_16x16x32_f16(a, bhhH[nt][kt], acc[nt], 0, 0, 0);
          accL[nt] = __builtin_amdgcn_mfma_f32_16x16x32_f16(a, bhhL[nt][kt], accL[nt], 0, 0, 0);
        }
      }
#pragma unroll
      for (int nt = 0; nt < NT; ++nt) acc[nt] += accL[nt] * (1.f / 1024.f);
    }

    // ---- gate preacts -> LDS. D frag: row=(l4)*4+r, col=l15 ----
#pragma unroll
    for (int nt = 0; nt < NT; ++nt)
#pragma unroll
      for (int r = 0; r < 4; ++r) {
        const int row = (l4 << 2) + r;
        gates_s[((w << 4) + row) * ST + (nt << 4) + l15] = acc[nt][r];
      }
    __syncthreads();

    // ---- cell update (PP items/thread) ----
    float hv[PP][2];
#pragma unroll
    for (int pp = 0; pp < PP; ++pp) {
      const int p = tid + (pp << 8);
      const int row = p >> LU;
#pragma unroll
      for (int j = 0; j < 2; ++j) {
        const int u = u0 + j;
        const float gI = gates_s[(0 * 16 + row) * ST + u] + bv[0][j];
        const float gF = gates_s[(1 * 16 + row) * ST + u] + bv[1][j];
        const float gG = gates_s[(2 * 16 + row) * ST + u] + bv[2][j];
        const float gO = gates_s[(3 * 16 + row) * ST + u] + bv[3][j];
        float cc = sigf(gF) * cs[pp][j] + sigf(gI) * tanh_f(gG);
        cs[pp][j] = cc;
        hv[pp][j] = sigf(gO) * tanh_f(cc);
      }
    }

    // ---- publish h(s) (tagged exch first), then bulk stores ----
    if (L == 1 && s >= 253) asm volatile("s_waitcnt vmcnt(0)" ::: "memory");
    {
      const u32 tagc = ((u32)(L * 512 + s) ^ TAGX) & 0x7FFu;
      const size_t pbase = ((size_t)((s & 1) * 2 + dirv)) * 256 * 128;
      const int g64 = (sl << LU) + upair;
#pragma unroll
      for (int pp = 0; pp < PP; ++pp) {
        const int p = tid + (pp << 8);
        const int row = p >> LU;
        const int b = (bg << 4) + row;
        const u32 w0 = ((__builtin_bit_cast(u32, hv[pp][0]) + 0x400u) & 0xFFFFF800u) | tagc;
        const u32 w1 = ((__builtin_bit_cast(u32, hv[pp][1]) + 0x400u) & 0xFFFFF800u) | tagc;
        const u64 pk = (u64)w0 | ((u64)w1 << 32);
        __hip_atomic_store(exch + pbase + b * 128 + g64, pk,
                           __ATOMIC_RELAXED, __HIP_MEMORY_SCOPE_AGENT);

        union { u16 hw[2]; u32 pkh; } uhh;
        uhh.hw[0] = __builtin_bit_cast(u16, (f16)hv[pp][0]);
        uhh.hw[1] = __builtin_bit_cast(u16, (f16)hv[pp][1]);
        const int uoff = (dirv << 7) + g64;
        if constexpr (L == 0) {
          ((u32*)hA)[((size_t)t_or * 256 + b) * 256 + uoff] = uhh.pkh;
        } else if constexpr (L == 1) {
          if (s < 256)
            ((u32*)aux)[((size_t)(dirv * 256 + s) * 256 + b) * 128 + g64] = uhh.pkh;
          else
            ((u32*)hA)[((size_t)t_or * 256 + b) * 256 + uoff] = uhh.pkh;
        } else {
          if (t_or == S_ - 1)
            ((u32*)l2out)[(size_t)b * 256 + uoff] = uhh.pkh;
        }
      }
    }

    // ---- L1: crossover MAGIC after h(254) globally posted ----
    if constexpr (L == 1) {
      if (s == 254) {
        asm volatile("s_waitcnt vmcnt(0)" ::: "memory");
        __syncthreads();
        if (tid == 0)
          __hip_atomic_store(xprog + dirv * 128 + (bg << 3) + sl, MAGIC_,
                             __ATOMIC_RELAXED, __HIP_MEMORY_SCOPE_AGENT);
      }
    }

    // ---- write x_s for s+1 and pre-compute its x-part ----
    if (pf) {
#pragma unroll
      for (int i = 0; i < XI; ++i) {
        const int G = tid + (i << 8);
        if (NG < 256 && G >= NG) break;
        const int row = G >> LG, g = G & (GPR - 1);
        *(f16x8*)&x_s[row * KIN + ((g ^ (row & 7)) << 3)] = xreg[i];
      }
      __syncthreads();
#pragma unroll
      for (int nt = 0; nt < NT; ++nt) accx[nt] = (f32x4){};
      X_MFMA(accx);
    }
  }
#undef X_MFMA
}

// ---------------------------------------------------------------------------
__global__ __launch_bounds__(256) void fc_head(
    const f16* __restrict__ l2out,   // [B][512]
    const float* __restrict__ fc1_w, const float* __restrict__ fc1_b,
    const float* __restrict__ fc2_w, const float* __restrict__ fc2_b,
    const float* __restrict__ fc3_w, const float* __restrict__ fc3_b,
    float* __restrict__ out)
{
  __shared__ float last[512];
  __shared__ float h1[256];
  __shared__ float h2[128];
  const int b = blockIdx.x;
  const int t = threadIdx.x;
  for (int i = t; i < 512; i += 256)
    last[i] = (float)l2out[(size_t)b * 512 + i];
  __syncthreads();
  {
    float a = fc1_b[t];
    for (int k = 0; k < 512; ++k) a = fmaf(last[k], fc1_w[t * 512 + k], a);
    h1[t] = fmaxf(a, 0.f);
  }
  __syncthreads();
  if (t < 128) {
    float a = fc2_b[t];
    for (int k = 0; k < 256; ++k) a = fmaf(h1[k], fc2_w[t * 256 + k], a);
    h2[t] = fmaxf(a, 0.f);
  }
  __syncthreads();
  if (t == 0) {
    float a = fc3_b[0];
    for (int k = 0; k < 128; ++k) a = fmaf(h2[k], fc3_w[k], a);
    out[b] = a;
  }
}

__global__ void sentinel(float* out, int n, float v) {
  const int i = blockIdx.x * blockDim.x + threadIdx.x;
  if (i < n) out[i] = v;
}

// ---------------------------------------------------------------------------
extern "C" void kernel_launch(void* const* d_in, const int* in_sizes, int n_in,
                              void* d_out, int out_size, void* d_ws, size_t ws_size,
                              hipStream_t stream) {
  (void)in_sizes; (void)n_in;
  const float* x      = (const float*)d_in[0];
  const float* w_ih0  = (const float*)d_in[1];
  const float* w_hh0  = (const float*)d_in[2];
  const float* b0     = (const float*)d_in[3];
  const float* w_ih_r = (const float*)d_in[4];
  const float* w_hh_r = (const float*)d_in[5];
  const float* b_r    = (const float*)d_in[6];
  const float* fc1_w  = (const float*)d_in[7];
  const float* fc1_b  = (const float*)d_in[8];
  const float* fc2_w  = (const float*)d_in[9];
  const float* fc2_b  = (const float*)d_in[10];
  const float* fc3_w  = (const float*)d_in[11];
  const float* fc3_b  = (const float*)d_in[12];
  float* out = (float*)d_out;

  // ---- workspace carve (bytes) ----
  const size_t off_hA    = 0;
  const size_t off_aux   = off_hA    + (size_t)512*256*512*2;      // 128 MiB
  const size_t off_xT    = off_aux   + (size_t)2*256*256*256*2;    // +64 MiB
  const size_t off_l2o   = off_xT    + (size_t)512*256*64*2;       // +16 MiB
  const size_t off_exch  = off_l2o   + (size_t)256*512*2;          // +0.25 MiB
  const size_t off_xprog = off_exch  + (size_t)2*2*256*128*8;      // +1 MiB
  const size_t need      = off_xprog + 1024;
  if (ws_size < need) {
    sentinel<<<1, 256, 0, stream>>>(out, out_size, (float)(ws_size >> 20));
    return;
  }
  char* ws = (char*)d_ws;
  f16* hA    = (f16*)(ws + off_hA);
  f16* aux   = (f16*)(ws + off_aux);
  f16* xT    = (f16*)(ws + off_xT);
  f16* l2out = (f16*)(ws + off_l2o);
  u64* exch  = (u64*)(ws + off_exch);
  u32* xprog = (u32*)(ws + off_xprog);

  // kill stale tags / MAGIC from previous replays (0xAA aliases no (L,s) tag)
  hipMemsetAsync(ws + off_exch, 0xAA, (size_t)2*2*256*128*8 + 1024, stream);

  transpose_x<<<512, 256, 0, stream>>>(x, xT);

  lstm_layer<0, 64, 4><<<128, 256, 0, stream>>>(
      xT, hA, aux, l2out, exch, xprog, w_ih0, w_hh0, b0);
  lstm_layer<1, 512, 8><<<256, 256, 0, stream>>>(
      xT, hA, aux, l2out, exch, xprog, w_ih_r, w_hh_r, b_r);
  lstm_layer<2, 512, 8><<<256, 256, 0, stream>>>(
      xT, hA, aux, l2out, exch, xprog,
      w_ih_r + (size_t)2 * 1024 * 512, w_hh_r + (size_t)2 * 1024 * 256,
      b_r + 2048);

  fc_head<<<B_, 256, 0, stream>>>(l2out, fc1_w, fc1_b, fc2_w, fc2_b, fc3_w, fc3_b, out);
}